// Round 1
// baseline (1148.196 us; speedup 1.0000x reference)
//
#include <hip/hip_runtime.h>
#include <math.h>

// Problem constants
#define NQ 40000
#define CDIM 256
#define HH 8
#define LVL 4
#define PPT 8
#define HD 32

// level geometry (compile-time)
__device__ __constant__ const int d_dummy = 0; // (unused)

static constexpr int HLa[4] = {128, 64, 32, 16};
static constexpr int HWa[4] = {16384, 4096, 1024, 256};
// v bases (in floats): level l block is [HH][Hl][Wl][HD] = 256*HW floats
static constexpr int VB[4] = {0, 4194304, 5242880, 5505024};
// total v floats = 5570560 (22.28 MB)

// ---------------------------------------------------------------------------
// Kernel 1: value projection  v[l][hh][y][x][dd] = sum_c f[c][y][x]*Wv[c][hh*32+dd] + bv
// block = 256 threads, 16 spatial positions per block
// ---------------------------------------------------------------------------
__global__ __launch_bounds__(256) void vproj_kernel(
    const float* __restrict__ f0, const float* __restrict__ f1,
    const float* __restrict__ f2, const float* __restrict__ f3,
    const float* __restrict__ Wv, const float* __restrict__ bv,
    float* __restrict__ v)
{
    __shared__ float fT[256 * 16];  // [c][hw] 16KB

    int bid = blockIdx.x;
    const float* f;
    int base, HWl, hw0;
    if (bid < 1024)      { f = f0; base = VB[0]; HWl = 16384; hw0 = bid * 16; }
    else if (bid < 1280) { f = f1; base = VB[1]; HWl = 4096;  hw0 = (bid - 1024) * 16; }
    else if (bid < 1344) { f = f2; base = VB[2]; HWl = 1024;  hw0 = (bid - 1280) * 16; }
    else                 { f = f3; base = VB[3]; HWl = 256;   hw0 = (bid - 1344) * 16; }

    int t = threadIdx.x;
    // stage f tile: fT[c][j] = f[c*HWl + hw0 + j]
    for (int k = 0; k < 16; ++k) {
        int idx = k * 256 + t;
        int c = idx >> 4, j = idx & 15;
        fT[idx] = f[c * HWl + hw0 + j];
    }
    __syncthreads();

    int to4 = (t & 63) * 4;   // output channel d (0..255), 4 per thread
    int hw4 = (t >> 6) * 4;   // spatial within tile, 4 per thread

    float4 bv4 = *(const float4*)(bv + to4);
    float acc[4][4];
    #pragma unroll
    for (int i = 0; i < 4; ++i) {
        acc[i][0] = bv4.x; acc[i][1] = bv4.y; acc[i][2] = bv4.z; acc[i][3] = bv4.w;
    }

    #pragma unroll 4
    for (int c = 0; c < 256; ++c) {
        float4 w4 = *(const float4*)(Wv + c * 256 + to4);
        float4 fv = *(const float4*)(fT + c * 16 + hw4);
        float fa[4] = {fv.x, fv.y, fv.z, fv.w};
        float wa[4] = {w4.x, w4.y, w4.z, w4.w};
        #pragma unroll
        for (int i = 0; i < 4; ++i)
            #pragma unroll
            for (int j = 0; j < 4; ++j)
                acc[i][j] += fa[i] * wa[j];
    }

    int hh = to4 >> 5, dd4 = to4 & 31;
    #pragma unroll
    for (int i = 0; i < 4; ++i) {
        int hw = hw0 + hw4 + i;
        float4 o = make_float4(acc[i][0], acc[i][1], acc[i][2], acc[i][3]);
        *(float4*)(v + base + (hh * HWl + hw) * 32 + dd4) = o;
    }
}

// ---------------------------------------------------------------------------
// Kernel 2: fused logits -> coords/weights -> sampling -> output projection
// block = 256 threads, 16 queries per block, 2500 blocks
// ---------------------------------------------------------------------------
__global__ __launch_bounds__(256) void msda_kernel(
    const float* __restrict__ query, const float* __restrict__ refp,
    const float* __restrict__ Woff,  const float* __restrict__ boff,
    const float* __restrict__ Wattn, const float* __restrict__ battn,
    const float* __restrict__ Wout,  const float* __restrict__ bout,
    const float* __restrict__ v,     float* __restrict__ out)
{
    __shared__ float qT[256 * 20];   // [c][qi] stride 20 (b128-aligned, bank-spread); reused as preT
    __shared__ float sC[4096 * 2];   // coords [qi][hh][l][p][xy]  32KB
    __shared__ float sW[16 * 256];   // weights [qi][hh*32+l*8+p]  16KB
    __shared__ float sR[16 * 8];     // ref     [qi][l][xy]        0.5KB

    int t = threadIdx.x;
    int n0 = blockIdx.x * 16;

    // ---- Phase A: stage q (transposed) + ref points ----
    for (int k = 0; k < 16; ++k) {
        int idx = k * 256 + t;          // qi*256 + c
        int qi = idx >> 8, c = idx & 255;
        qT[c * 20 + qi] = query[(n0 + qi) * 256 + c];
    }
    if (t < 128) sR[t] = refp[n0 * 8 + t];
    __syncthreads();

    int to4 = (t & 63) * 4;   // 4 consecutive outputs (0..255)
    int tq4 = (t >> 6) * 4;   // 4 consecutive queries (0..15), constant per wave

    // ---- Phase B: logits GEMM (3 output groups at once) ----
    float a0[4][4], a1[4][4], a2[4][4];   // off[hh0..3], off[hh4..7], attn
    {
        float4 b0 = *(const float4*)(boff + to4);
        float4 b1 = *(const float4*)(boff + 256 + to4);
        float4 b2 = *(const float4*)(battn + to4);
        #pragma unroll
        for (int i = 0; i < 4; ++i) {
            a0[i][0] = b0.x; a0[i][1] = b0.y; a0[i][2] = b0.z; a0[i][3] = b0.w;
            a1[i][0] = b1.x; a1[i][1] = b1.y; a1[i][2] = b1.z; a1[i][3] = b1.w;
            a2[i][0] = b2.x; a2[i][1] = b2.y; a2[i][2] = b2.z; a2[i][3] = b2.w;
        }
    }

    #pragma unroll 2
    for (int c = 0; c < 256; ++c) {
        float4 q4 = *(const float4*)(qT + c * 20 + tq4);   // broadcast within wave
        float4 w0 = *(const float4*)(Woff + c * 512 + to4);
        float4 w1 = *(const float4*)(Woff + c * 512 + 256 + to4);
        float4 w2 = *(const float4*)(Wattn + c * 256 + to4);
        float qa[4] = {q4.x, q4.y, q4.z, q4.w};
        float wa0[4] = {w0.x, w0.y, w0.z, w0.w};
        float wa1[4] = {w1.x, w1.y, w1.z, w1.w};
        float wa2[4] = {w2.x, w2.y, w2.z, w2.w};
        #pragma unroll
        for (int i = 0; i < 4; ++i) {
            #pragma unroll
            for (int j = 0; j < 4; ++j) {
                a0[i][j] += qa[i] * wa0[j];
                a1[i][j] += qa[i] * wa1[j];
                a2[i][j] += qa[i] * wa2[j];
            }
        }
    }

    // ---- Phase C: epilogue -> coords (tanh) + softmax weights ----
    // off logits: o = hh*64 + l*16 + p*2 + xy  (pass0: hh 0..3; pass1: hh 4..7)
    #pragma unroll
    for (int i = 0; i < 4; ++i) {
        int qi = tq4 + i;
        #pragma unroll
        for (int j = 0; j < 4; j += 2) {
            int o = to4 + j;                // even -> xy = 0
            int pp = (o >> 1) & 7;
            int l  = (o >> 4) & 3;
            int hh = o >> 6;                // 0..3
            float rx = sR[qi * 8 + l * 2 + 0];
            float ry = sR[qi * 8 + l * 2 + 1];
            float2 c0, c1;
            c0.x = rx + tanhf(a0[i][j])     * 0.25f;
            c0.y = ry + tanhf(a0[i][j + 1]) * 0.25f;
            c1.x = rx + tanhf(a1[i][j])     * 0.25f;
            c1.y = ry + tanhf(a1[i][j + 1]) * 0.25f;
            *(float2*)(sC + (((qi * 8 + hh) * 4 + l) * 8 + pp) * 2)       = c0;
            *(float2*)(sC + (((qi * 8 + hh + 4) * 4 + l) * 8 + pp) * 2)   = c1;
        }
    }
    // attn softmax over P=8: thread holds 4 of a group of 8; partner = lane^1
    #pragma unroll
    for (int i = 0; i < 4; ++i) {
        float m = fmaxf(fmaxf(a2[i][0], a2[i][1]), fmaxf(a2[i][2], a2[i][3]));
        m = fmaxf(m, __shfl_xor(m, 1));
        float e0 = expf(a2[i][0] - m);
        float e1 = expf(a2[i][1] - m);
        float e2 = expf(a2[i][2] - m);
        float e3 = expf(a2[i][3] - m);
        float s = e0 + e1 + e2 + e3;
        s += __shfl_xor(s, 1);
        float inv = 1.0f / s;
        float4 wv = make_float4(e0 * inv, e1 * inv, e2 * inv, e3 * inv);
        *(float4*)(sW + (tq4 + i) * 256 + to4) = wv;
    }
    __syncthreads();

    // ---- Phase D: bilinear sampling, accumulate over (l, p) ----
    {
        int hh = t >> 5, dd = t & 31;
        for (int qi = 0; qi < 16; ++qi) {
            float acc = 0.0f;
            #pragma unroll
            for (int l = 0; l < LVL; ++l) {
                const int Wl = HLa[l];
                const int Hl = HLa[l];
                const float* vl = v + VB[l] + hh * (Hl * Wl) * 32 + dd;
                const float scl = 0.5f * (float)(Wl - 1);
                #pragma unroll
                for (int p = 0; p < PPT; ++p) {
                    int si = ((qi * 8 + hh) * 4 + l) * 8 + p;
                    float cx = sC[si * 2 + 0];
                    float cy = sC[si * 2 + 1];
                    float w  = sW[qi * 256 + hh * 32 + l * 8 + p];
                    float xx = (cx + 1.0f) * scl;
                    float yy = (cy + 1.0f) * scl;
                    float x0f = floorf(xx), y0f = floorf(yy);
                    int x0 = (int)x0f, y0 = (int)y0f;
                    float fx = xx - x0f, fy = yy - y0f;
                    int xc0 = min(max(x0, 0), Wl - 1);
                    int xc1 = min(max(x0 + 1, 0), Wl - 1);
                    int yc0 = min(max(y0, 0), Hl - 1);
                    int yc1 = min(max(y0 + 1, 0), Hl - 1);
                    bool bx0 = (x0 >= 0) && (x0 < Wl);
                    bool bx1 = (x0 + 1 >= 0) && (x0 + 1 < Wl);
                    bool by0 = (y0 >= 0) && (y0 < Hl);
                    bool by1 = (y0 + 1 >= 0) && (y0 + 1 < Hl);
                    float w00 = (bx0 && by0) ? (1.0f - fx) * (1.0f - fy) : 0.0f;
                    float w01 = (bx1 && by0) ? fx * (1.0f - fy) : 0.0f;
                    float w10 = (bx0 && by1) ? (1.0f - fx) * fy : 0.0f;
                    float w11 = (bx1 && by1) ? fx * fy : 0.0f;
                    float g00 = vl[(yc0 * Wl + xc0) * 32];
                    float g01 = vl[(yc0 * Wl + xc1) * 32];
                    float g10 = vl[(yc1 * Wl + xc0) * 32];
                    float g11 = vl[(yc1 * Wl + xc1) * 32];
                    acc += w * (w00 * g00 + w01 * g01 + w10 * g10 + w11 * g11);
                }
            }
            qT[(hh * 32 + dd) * 20 + qi] = acc;   // preT[c][qi] (reuse qT arena)
        }
    }
    __syncthreads();

    // ---- Phase E: output projection  out = preT^T @ Wout + bout ----
    {
        float accO[4][4];
        float4 bo = *(const float4*)(bout + to4);
        #pragma unroll
        for (int i = 0; i < 4; ++i) {
            accO[i][0] = bo.x; accO[i][1] = bo.y; accO[i][2] = bo.z; accO[i][3] = bo.w;
        }
        #pragma unroll 2
        for (int c = 0; c < 256; ++c) {
            float4 x4 = *(const float4*)(qT + c * 20 + tq4);
            float4 w4 = *(const float4*)(Wout + c * 256 + to4);
            float xa[4] = {x4.x, x4.y, x4.z, x4.w};
            float wa[4] = {w4.x, w4.y, w4.z, w4.w};
            #pragma unroll
            for (int i = 0; i < 4; ++i)
                #pragma unroll
                for (int j = 0; j < 4; ++j)
                    accO[i][j] += xa[i] * wa[j];
        }
        #pragma unroll
        for (int i = 0; i < 4; ++i) {
            float4 o = make_float4(accO[i][0], accO[i][1], accO[i][2], accO[i][3]);
            *(float4*)(out + (n0 + tq4 + i) * 256 + to4) = o;
        }
    }
}

// ---------------------------------------------------------------------------
extern "C" void kernel_launch(void* const* d_in, const int* in_sizes, int n_in,
                              void* d_out, int out_size, void* d_ws, size_t ws_size,
                              hipStream_t stream) {
    const float* query = (const float*)d_in[0];
    const float* refp  = (const float*)d_in[1];
    const float* f0    = (const float*)d_in[2];
    const float* f1    = (const float*)d_in[3];
    const float* f2    = (const float*)d_in[4];
    const float* f3    = (const float*)d_in[5];
    const float* Woff  = (const float*)d_in[6];
    const float* boff  = (const float*)d_in[7];
    const float* Wattn = (const float*)d_in[8];
    const float* battn = (const float*)d_in[9];
    const float* Wval  = (const float*)d_in[10];
    const float* bval  = (const float*)d_in[11];
    const float* Wout  = (const float*)d_in[12];
    const float* bout  = (const float*)d_in[13];
    float* v = (float*)d_ws;                 // 5570560 floats = 22.28 MB
    float* outp = (float*)d_out;

    vproj_kernel<<<1360, 256, 0, stream>>>(f0, f1, f2, f3, Wval, bval, v);
    msda_kernel<<<2500, 256, 0, stream>>>(query, refp, Woff, boff, Wattn, battn,
                                          Wout, bout, v, outp);
}

// Round 2
// 864.357 us; speedup vs baseline: 1.3284x; 1.3284x over previous
//
#include <hip/hip_runtime.h>
#include <hip/hip_fp16.h>
#include <math.h>

// Problem constants
#define NQ 40000
#define CDIM 256
#define HH 8
#define LVL 4
#define PPT 8
#define HD 32

static constexpr int HLa[4] = {128, 64, 32, 16};
static constexpr int HWa[4] = {16384, 4096, 1024, 256};
// v bases (in floats): level l block is [HH][Hl][Wl][HD] = 256*HW floats
static constexpr int VB[4] = {0, 4194304, 5242880, 5505024};
// total v floats = 5570560 (22.28 MB)

__device__ __forceinline__ float fast_tanh(float x) {
    float xc = fminf(fmaxf(x, -15.f), 15.f);
    float e = __expf(2.f * xc);
    return (e - 1.f) / (e + 1.f);
}

// ---------------------------------------------------------------------------
// Kernel 1: value projection  v[l][hh][y][x][dd] = sum_c f[c][y][x]*Wv[c][hh*32+dd] + bv
// ---------------------------------------------------------------------------
__global__ __launch_bounds__(256) void vproj_kernel(
    const float* __restrict__ f0, const float* __restrict__ f1,
    const float* __restrict__ f2, const float* __restrict__ f3,
    const float* __restrict__ Wv, const float* __restrict__ bv,
    float* __restrict__ v)
{
    __shared__ float fT[256 * 16];  // [c][hw] 16KB

    int bid = blockIdx.x;
    const float* f;
    int base, HWl, hw0;
    if (bid < 1024)      { f = f0; base = VB[0]; HWl = 16384; hw0 = bid * 16; }
    else if (bid < 1280) { f = f1; base = VB[1]; HWl = 4096;  hw0 = (bid - 1024) * 16; }
    else if (bid < 1344) { f = f2; base = VB[2]; HWl = 1024;  hw0 = (bid - 1280) * 16; }
    else                 { f = f3; base = VB[3]; HWl = 256;   hw0 = (bid - 1344) * 16; }

    int t = threadIdx.x;
    for (int k = 0; k < 16; ++k) {
        int idx = k * 256 + t;
        int c = idx >> 4, j = idx & 15;
        fT[idx] = f[c * HWl + hw0 + j];
    }
    __syncthreads();

    int to4 = (t & 63) * 4;   // output channel d (0..255), 4 per thread
    int hw4 = (t >> 6) * 4;   // spatial within tile, 4 per thread

    float4 bv4 = *(const float4*)(bv + to4);
    float acc[4][4];
    #pragma unroll
    for (int i = 0; i < 4; ++i) {
        acc[i][0] = bv4.x; acc[i][1] = bv4.y; acc[i][2] = bv4.z; acc[i][3] = bv4.w;
    }

    #pragma unroll 4
    for (int c = 0; c < 256; ++c) {
        float4 w4 = *(const float4*)(Wv + c * 256 + to4);
        float4 fv = *(const float4*)(fT + c * 16 + hw4);
        float fa[4] = {fv.x, fv.y, fv.z, fv.w};
        float wa[4] = {w4.x, w4.y, w4.z, w4.w};
        #pragma unroll
        for (int i = 0; i < 4; ++i)
            #pragma unroll
            for (int j = 0; j < 4; ++j)
                acc[i][j] += fa[i] * wa[j];
    }

    int hh = to4 >> 5, dd4 = to4 & 31;
    #pragma unroll
    for (int i = 0; i < 4; ++i) {
        int hw = hw0 + hw4 + i;
        float4 o = make_float4(acc[i][0], acc[i][1], acc[i][2], acc[i][3]);
        *(float4*)(v + base + (hh * HWl + hw) * 32 + dd4) = o;
    }
}

// ---------------------------------------------------------------------------
// Kernel 2: fused logits -> pack -> sample (4 passes over hh-pairs) -> out proj
// block = 256 threads, 16 queries, 2500 blocks.
// LDS arena (29.2 KB total):
//   qT   [16][256] fp32 : staged query -> (aliased) softmax weights sW -> preT
//   sPI  [1024] u32     : packed idx|dx|dy per sample (one hh-pair pass)
//   sPW  [1024] uint2   : 4 x fp16 corner weights (pre-multiplied by attn w)
//   sR   [128] fp32     : reference points
// ---------------------------------------------------------------------------
__global__ __launch_bounds__(256, 4) void msda_kernel(
    const float* __restrict__ query, const float* __restrict__ refp,
    const float* __restrict__ Woff,  const float* __restrict__ boff,
    const float* __restrict__ Wattn, const float* __restrict__ battn,
    const float* __restrict__ Wout,  const float* __restrict__ bout,
    const float* __restrict__ v,     float* __restrict__ out)
{
    __shared__ float smem[4096 + 1024 + 2048 + 128];
    float* qT  = smem;                       // [16][256], aliased as sW then preT
    uint*  sPI = (uint*)(smem + 4096);       // [1024]
    uint2* sPW = (uint2*)(smem + 5120);      // [1024] (8B aligned: 20480 % 8 == 0)
    float* sR  = smem + 5120 + 2048;         // [128]

    int t = threadIdx.x;
    int n0 = blockIdx.x * 16;

    // ---- Phase A: stage q row-major + ref points ----
    for (int k = 0; k < 16; ++k) {
        qT[k * 256 + t] = query[(n0 + k) * 256 + t];
    }
    if (t < 128) sR[t] = refp[n0 * 8 + t];
    __syncthreads();

    int to4 = (t & 63) * 4;   // 4 consecutive outputs (0..255)
    int tq4 = (t >> 6) * 4;   // 4 consecutive queries (0..15), wave-constant

    // ---- Phase B: logits GEMM ----
    float a0[4][4], a1[4][4], a2[4][4];   // off[hh0..3], off[hh4..7], attn
    {
        float4 b0 = *(const float4*)(boff + to4);
        float4 b1 = *(const float4*)(boff + 256 + to4);
        float4 b2 = *(const float4*)(battn + to4);
        #pragma unroll
        for (int i = 0; i < 4; ++i) {
            a0[i][0] = b0.x; a0[i][1] = b0.y; a0[i][2] = b0.z; a0[i][3] = b0.w;
            a1[i][0] = b1.x; a1[i][1] = b1.y; a1[i][2] = b1.z; a1[i][3] = b1.w;
            a2[i][0] = b2.x; a2[i][1] = b2.y; a2[i][2] = b2.z; a2[i][3] = b2.w;
        }
    }

    for (int c = 0; c < 256; c += 4) {
        float4 q4[4];
        #pragma unroll
        for (int i = 0; i < 4; ++i)
            q4[i] = *(const float4*)(qT + (tq4 + i) * 256 + c);
        #pragma unroll
        for (int cc = 0; cc < 4; ++cc) {
            float4 w0 = *(const float4*)(Woff + (c + cc) * 512 + to4);
            float4 w1 = *(const float4*)(Woff + (c + cc) * 512 + 256 + to4);
            float4 w2 = *(const float4*)(Wattn + (c + cc) * 256 + to4);
            float wa0[4] = {w0.x, w0.y, w0.z, w0.w};
            float wa1[4] = {w1.x, w1.y, w1.z, w1.w};
            float wa2[4] = {w2.x, w2.y, w2.z, w2.w};
            #pragma unroll
            for (int i = 0; i < 4; ++i) {
                float qa = ((const float*)&q4[i])[cc];
                #pragma unroll
                for (int j = 0; j < 4; ++j) {
                    a0[i][j] += qa * wa0[j];
                    a1[i][j] += qa * wa1[j];
                    a2[i][j] += qa * wa2[j];
                }
            }
        }
    }
    __syncthreads();   // qT (staged q) dead; arena becomes sW

    // ---- Phase C1: softmax over P=8 -> sW (aliased on qT arena) ----
    #pragma unroll
    for (int i = 0; i < 4; ++i) {
        float m = fmaxf(fmaxf(a2[i][0], a2[i][1]), fmaxf(a2[i][2], a2[i][3]));
        m = fmaxf(m, __shfl_xor(m, 1));
        float e0 = __expf(a2[i][0] - m);
        float e1 = __expf(a2[i][1] - m);
        float e2 = __expf(a2[i][2] - m);
        float e3 = __expf(a2[i][3] - m);
        float s = e0 + e1 + e2 + e3;
        s += __shfl_xor(s, 1);
        float inv = 1.0f / s;
        float4 wv = make_float4(e0 * inv, e1 * inv, e2 * inv, e3 * inv);
        *(float4*)(qT + (tq4 + i) * 256 + to4) = wv;   // sW[qi][o2]
    }
    __syncthreads();

    // ---- Phases P/D: 4 passes over hh-pairs {2k, 2k+1} ----
    int h0 = to4 >> 6;            // 0..3 (off-logit head within a0/a1)
    int lP = (to4 >> 4) & 3;      // level owned by this thread's off logits
    int ddS = t & 31;             // sampling: channel
    int hhpS = (t >> 5) & 1;      // sampling: which head of the pair
    int qgS = t >> 6;             // sampling: query group (4 queries)

    for (int k = 0; k < 4; ++k) {
        // -- pack: precompute sample params once (active: half the threads) --
        if ((h0 >> 1) == (k & 1)) {
            int hh = 2 * k + (h0 & 1);
            const int Wl = HLa[lP];
            const float scl = 0.5f * (float)(Wl - 1);
            #pragma unroll
            for (int i = 0; i < 4; ++i) {
                int qi = tq4 + i;
                float rx = sR[qi * 8 + lP * 2 + 0];
                float ry = sR[qi * 8 + lP * 2 + 1];
                #pragma unroll
                for (int jh = 0; jh < 2; ++jh) {
                    int j = jh * 2;
                    float lx = (k < 2) ? a0[i][j]     : a1[i][j];
                    float ly = (k < 2) ? a0[i][j + 1] : a1[i][j + 1];
                    int p = ((to4 + j) >> 1) & 7;
                    float w = qT[qi * 256 + hh * 32 + lP * 8 + p];  // sW read
                    float cx = rx + fast_tanh(lx) * 0.25f;
                    float cy = ry + fast_tanh(ly) * 0.25f;
                    float xx = (cx + 1.0f) * scl;
                    float yy = (cy + 1.0f) * scl;
                    float x0f = floorf(xx), y0f = floorf(yy);
                    float fx = xx - x0f, fy = yy - y0f;
                    int x0 = (int)x0f, y0 = (int)y0f;
                    int xc0 = min(max(x0, 0), Wl - 1);
                    int xc1 = min(max(x0 + 1, 0), Wl - 1);
                    int yc0 = min(max(y0, 0), Wl - 1);
                    int yc1 = min(max(y0 + 1, 0), Wl - 1);
                    bool bx0 = (x0 >= 0) & (x0 < Wl);
                    bool bx1 = (x0 + 1 < Wl) & (x0 + 1 >= 0);
                    bool by0 = (y0 >= 0) & (y0 < Wl);
                    bool by1 = (y0 + 1 < Wl) & (y0 + 1 >= 0);
                    float w00 = (bx0 && by0) ? (1.f - fx) * (1.f - fy) * w : 0.f;
                    float w01 = (bx1 && by0) ? fx * (1.f - fy) * w : 0.f;
                    float w10 = (bx0 && by1) ? (1.f - fx) * fy * w : 0.f;
                    float w11 = (bx1 && by1) ? fx * fy * w : 0.f;
                    uint dxb = (uint)(xc1 - xc0);
                    uint dyb = (uint)(yc1 - yc0);
                    uint pw = (uint)(yc0 * Wl + xc0) | (dxb << 14) | (dyb << 15);
                    int s = ((qi * 2 + (hh & 1)) * 4 + lP) * 8 + p;
                    sPI[s] = pw;
                    __half2 ha = __floats2half2_rn(w00, w01);
                    __half2 hb = __floats2half2_rn(w10, w11);
                    sPW[s] = make_uint2(*(uint*)&ha, *(uint*)&hb);
                }
            }
        }
        __syncthreads();

        // -- sample: gather + blend, coalesced over 32 channels --
        {
            int hh = 2 * k + hhpS;
            #pragma unroll
            for (int i = 0; i < 4; ++i) {
                int qi = qgS * 4 + i;
                float accc[4] = {0.f, 0.f, 0.f, 0.f};
                #pragma unroll
                for (int l = 0; l < 4; ++l) {
                    const int Wl = HLa[l];
                    const float* vl = v + VB[l] + hh * HWa[l] * 32 + ddS;
                    #pragma unroll
                    for (int p = 0; p < 8; ++p) {
                        int s = ((qi * 2 + hhpS) * 4 + l) * 8 + p;
                        uint pw = sPI[s];
                        uint2 ww = sPW[s];
                        int idx = pw & 0x3FFF;
                        int dx  = (pw >> 14) & 1;
                        int dyo = ((pw >> 15) & 1) * Wl;
                        const float* b00 = vl + idx * 32;
                        float g00 = b00[0];
                        float g01 = b00[dx * 32];
                        float g10 = b00[dyo * 32];
                        float g11 = b00[(dx + dyo) * 32];
                        float2 fa = __half22float2(*(__half2*)&ww.x);
                        float2 fb = __half22float2(*(__half2*)&ww.y);
                        accc[0] += fa.x * g00;
                        accc[1] += fa.y * g01;
                        accc[2] += fb.x * g10;
                        accc[3] += fb.y * g11;
                    }
                }
                // preT[qi][hh*32+dd]  (cols [64k, 64k+64) — disjoint from
                // sW cols >= 64(k+1) still needed by later pack passes)
                qT[qi * 256 + hh * 32 + ddS] =
                    (accc[0] + accc[1]) + (accc[2] + accc[3]);
            }
        }
        __syncthreads();
    }

    // ---- Phase E: output projection  out = preT @ Wout + bout ----
    {
        float accO[4][4];
        float4 bo = *(const float4*)(bout + to4);
        #pragma unroll
        for (int i = 0; i < 4; ++i) {
            accO[i][0] = bo.x; accO[i][1] = bo.y; accO[i][2] = bo.z; accO[i][3] = bo.w;
        }
        for (int c = 0; c < 256; c += 4) {
            float4 x4[4];
            #pragma unroll
            for (int i = 0; i < 4; ++i)
                x4[i] = *(const float4*)(qT + (tq4 + i) * 256 + c);
            #pragma unroll
            for (int cc = 0; cc < 4; ++cc) {
                float4 w4 = *(const float4*)(Wout + (c + cc) * 256 + to4);
                float wa[4] = {w4.x, w4.y, w4.z, w4.w};
                #pragma unroll
                for (int i = 0; i < 4; ++i) {
                    float xa = ((const float*)&x4[i])[cc];
                    #pragma unroll
                    for (int j = 0; j < 4; ++j)
                        accO[i][j] += xa * wa[j];
                }
            }
        }
        #pragma unroll
        for (int i = 0; i < 4; ++i) {
            float4 o = make_float4(accO[i][0], accO[i][1], accO[i][2], accO[i][3]);
            *(float4*)(out + (n0 + tq4 + i) * 256 + to4) = o;
        }
    }
}

// ---------------------------------------------------------------------------
extern "C" void kernel_launch(void* const* d_in, const int* in_sizes, int n_in,
                              void* d_out, int out_size, void* d_ws, size_t ws_size,
                              hipStream_t stream) {
    const float* query = (const float*)d_in[0];
    const float* refp  = (const float*)d_in[1];
    const float* f0    = (const float*)d_in[2];
    const float* f1    = (const float*)d_in[3];
    const float* f2    = (const float*)d_in[4];
    const float* f3    = (const float*)d_in[5];
    const float* Woff  = (const float*)d_in[6];
    const float* boff  = (const float*)d_in[7];
    const float* Wattn = (const float*)d_in[8];
    const float* battn = (const float*)d_in[9];
    const float* Wval  = (const float*)d_in[10];
    const float* bval  = (const float*)d_in[11];
    const float* Wout  = (const float*)d_in[12];
    const float* bout  = (const float*)d_in[13];
    float* v = (float*)d_ws;                 // 5570560 floats = 22.28 MB
    float* outp = (float*)d_out;

    vproj_kernel<<<1360, 256, 0, stream>>>(f0, f1, f2, f3, Wval, bval, v);
    msda_kernel<<<2500, 256, 0, stream>>>(query, refp, Woff, boff, Wattn, battn,
                                          Wout, bout, v, outp);
}

// Round 5
// 540.828 us; speedup vs baseline: 2.1230x; 1.5982x over previous
//
#include <hip/hip_runtime.h>
#include <hip/hip_fp16.h>
#include <math.h>

// Problem constants
#define NQ 40000

typedef short s16x8 __attribute__((ext_vector_type(8)));
typedef float f32x4 __attribute__((ext_vector_type(4)));

static constexpr int HLa[4] = {128, 64, 32, 16};
static constexpr int HWa[4] = {16384, 4096, 1024, 256};
// v bases (element units): level block is [HH][Hl][Wl][32]
static constexpr int VB[4] = {0, 4194304, 5242880, 5505024};
// total v elements = 5570560

__device__ __forceinline__ short bf16hi(float x) {
    union { float f; unsigned u; } v; v.f = x;
    unsigned r = v.u + 0x7FFFu + ((v.u >> 16) & 1u);
    return (short)(r >> 16);
}
__device__ __forceinline__ float bf16f(short s) {
    union { unsigned u; float f; } v; v.u = ((unsigned)(unsigned short)s) << 16;
    return v.f;
}
__device__ __forceinline__ float fast_tanh(float x) {
    float xc = fminf(fmaxf(x, -15.f), 15.f);
    float e = __expf(2.f * xc);
    return (e - 1.f) / (e + 1.f);
}
#define MFMA16(a, b, c) __builtin_amdgcn_mfma_f32_16x16x32_bf16(a, b, c, 0, 0, 0)

// ---------------------------------------------------------------------------
// Kernel 0: weight prep — transpose [C][N] -> [N][C], bf16 hi/lo split.
// rows: [0,512) = W_off cols, [512,768) = W_attn cols, [768,1024) = W_out cols
// ---------------------------------------------------------------------------
__global__ __launch_bounds__(256) void prep_w(
    const float* __restrict__ Woff, const float* __restrict__ Wattn,
    const float* __restrict__ Wout, short* __restrict__ WtH, short* __restrict__ WtL)
{
    int r = blockIdx.x, c = threadIdx.x;
    float x;
    if (r < 512)      x = Woff[c * 512 + r];
    else if (r < 768) x = Wattn[c * 256 + (r - 512)];
    else              x = Wout[c * 256 + (r - 768)];
    short hi = bf16hi(x);
    WtH[r * 256 + c] = hi;
    WtL[r * 256 + c] = bf16hi(x - bf16f(hi));
}

// ---------------------------------------------------------------------------
// Kernel 1: value projection -> fp16 table  v[l][hh][y][x][dd]
// ---------------------------------------------------------------------------
__global__ __launch_bounds__(256) void vproj_kernel(
    const float* __restrict__ f0, const float* __restrict__ f1,
    const float* __restrict__ f2, const float* __restrict__ f3,
    const float* __restrict__ Wv, const float* __restrict__ bv,
    __half* __restrict__ v)
{
    __shared__ float fT[256 * 16];  // [c][hw] 16KB

    int bid = blockIdx.x;
    const float* f;
    int base, HWl, hw0;
    if (bid < 1024)      { f = f0; base = VB[0]; HWl = 16384; hw0 = bid * 16; }
    else if (bid < 1280) { f = f1; base = VB[1]; HWl = 4096;  hw0 = (bid - 1024) * 16; }
    else if (bid < 1344) { f = f2; base = VB[2]; HWl = 1024;  hw0 = (bid - 1280) * 16; }
    else                 { f = f3; base = VB[3]; HWl = 256;   hw0 = (bid - 1344) * 16; }

    int t = threadIdx.x;
    for (int k = 0; k < 16; ++k) {
        int idx = k * 256 + t;
        int c = idx >> 4, j = idx & 15;
        fT[idx] = f[c * HWl + hw0 + j];
    }
    __syncthreads();

    int to4 = (t & 63) * 4;
    int hw4 = (t >> 6) * 4;

    float4 bv4 = *(const float4*)(bv + to4);
    float acc[4][4];
    #pragma unroll
    for (int i = 0; i < 4; ++i) {
        acc[i][0] = bv4.x; acc[i][1] = bv4.y; acc[i][2] = bv4.z; acc[i][3] = bv4.w;
    }

    #pragma unroll 4
    for (int c = 0; c < 256; ++c) {
        float4 w4 = *(const float4*)(Wv + c * 256 + to4);
        float4 fv = *(const float4*)(fT + c * 16 + hw4);
        float fa[4] = {fv.x, fv.y, fv.z, fv.w};
        float wa[4] = {w4.x, w4.y, w4.z, w4.w};
        #pragma unroll
        for (int i = 0; i < 4; ++i)
            #pragma unroll
            for (int j = 0; j < 4; ++j)
                acc[i][j] += fa[i] * wa[j];
    }

    int hh = to4 >> 5, dd4 = to4 & 31;
    #pragma unroll
    for (int i = 0; i < 4; ++i) {
        int hw = hw0 + hw4 + i;
        __half2 h0 = __floats2half2_rn(acc[i][0], acc[i][1]);
        __half2 h1 = __floats2half2_rn(acc[i][2], acc[i][3]);
        uint2 st = make_uint2(*(unsigned*)&h0, *(unsigned*)&h1);
        *(uint2*)(v + base + (hh * HWl + hw) * 32 + dd4) = st;
    }
}

// ---------------------------------------------------------------------------
// Kernel 2: MFMA logits (hi/lo) -> fp32 softmax -> per-pass LDS dump ->
//           parallel pack -> fp16-table gather (fp32 blend) -> MFMA out proj
// block = 256 threads (4 waves), 16 queries, 2500 blocks. LDS 37.9 KB.
// ---------------------------------------------------------------------------
__global__ __launch_bounds__(256, 4) void msda_kernel(
    const float* __restrict__ query, const float* __restrict__ refp,
    const float* __restrict__ boff,  const float* __restrict__ battn,
    const float* __restrict__ bout,
    const short* __restrict__ WtH,   const short* __restrict__ WtL,
    const __half* __restrict__ v,    float* __restrict__ out)
{
    __shared__ __align__(16) char lds[37888];
    short*    sQh  = (short*)lds;                // [16][264] bf16 hi (A-frags)
    short*    sQl  = (short*)(lds + 8448);       // [16][264] bf16 lo
    float*    offL = (float*)lds;                // [16][132] pass-scoped off logits (alias)
    uint2*    sPWh = (uint2*)(lds + 8448);       // [1024] fp16 corner-wt pairs (alias)
    float*    sWf  = (float*)(lds + 16896);      // [16][256] fp32 attn wts -> preT
    unsigned* sPI  = (unsigned*)(lds + 33280);   // [1024] packed idx|dx|dy
    float*    sR   = (float*)(lds + 37376);      // [128] ref points

    const int t = threadIdx.x;
    const int n0 = blockIdx.x * 16;
    const int wv = t >> 6, lane = t & 63;
    const int mrow = lane & 15, kg = lane >> 4;

    // ---- Stage: query -> bf16 hi/lo LDS, ref points ----
    for (int k2 = 0; k2 < 16; ++k2) {
        float x = query[(n0 + k2) * 256 + t];
        short hi = bf16hi(x);
        sQh[k2 * 264 + t] = hi;
        sQl[k2 * 264 + t] = bf16hi(x - bf16f(hi));
    }
    if (t < 128) sR[t] = refp[n0 * 8 + t];
    __syncthreads();

    // ---- Phase B: logits via MFMA (hi/lo 3-pass for off AND attn) ----
    f32x4 accO[8], accA[4];
    {
        f32x4 z = {0.f, 0.f, 0.f, 0.f};
        #pragma unroll
        for (int j = 0; j < 8; ++j) accO[j] = z;
        #pragma unroll
        for (int j = 0; j < 4; ++j) accA[j] = z;
    }
    {
        const short* offH = WtH + (wv * 128 + mrow) * 256 + kg * 8;
        const short* offLo = WtL + (wv * 128 + mrow) * 256 + kg * 8;
        const short* attH = WtH + (512 + wv * 64 + mrow) * 256 + kg * 8;
        const short* attL = WtL + (512 + wv * 64 + mrow) * 256 + kg * 8;
        const int aoff = mrow * 264 + kg * 8;
        #pragma unroll
        for (int kk = 0; kk < 8; ++kk) {
            s16x8 ah = *(const s16x8*)(sQh + aoff + kk * 32);
            s16x8 al = *(const s16x8*)(sQl + aoff + kk * 32);
            #pragma unroll
            for (int j = 0; j < 8; ++j) {
                s16x8 bh = *(const s16x8*)(offH + j * 4096 + kk * 32);
                s16x8 bl = *(const s16x8*)(offLo + j * 4096 + kk * 32);
                accO[j] = MFMA16(ah, bh, accO[j]);
                accO[j] = MFMA16(al, bh, accO[j]);
                accO[j] = MFMA16(ah, bl, accO[j]);
            }
            #pragma unroll
            for (int ja = 0; ja < 4; ++ja) {
                s16x8 bh = *(const s16x8*)(attH + ja * 4096 + kk * 32);
                s16x8 bl = *(const s16x8*)(attL + ja * 4096 + kk * 32);
                accA[ja] = MFMA16(ah, bh, accA[ja]);
                accA[ja] = MFMA16(al, bh, accA[ja]);
                accA[ja] = MFMA16(ah, bl, accA[ja]);
            }
        }
    }
    // biases (per-column; D layout: col = mrow, rows = kg*4 + r)
    #pragma unroll
    for (int j = 0; j < 8; ++j) {
        float bb = boff[wv * 128 + j * 16 + mrow];
        #pragma unroll
        for (int r = 0; r < 4; ++r) accO[j][r] += bb;
    }
    #pragma unroll
    for (int ja = 0; ja < 4; ++ja) {
        float bb = battn[wv * 64 + ja * 16 + mrow];
        #pragma unroll
        for (int r = 0; r < 4; ++r) accA[ja][r] += bb;
    }

    // ---- Softmax over P=8 (8-lane groups), fp32 weights to sWf ----
    #pragma unroll
    for (int ja = 0; ja < 4; ++ja) {
        int hh = 2 * wv + (ja >> 1);
        int l  = ((ja & 1) << 1) | (mrow >> 3);
        int p  = mrow & 7;
        #pragma unroll
        for (int r = 0; r < 4; ++r) {
            float x = accA[ja][r];
            float m = fmaxf(x, __shfl_xor(x, 1));
            m = fmaxf(m, __shfl_xor(m, 2));
            m = fmaxf(m, __shfl_xor(m, 4));
            float e = __expf(x - m);
            float s = e + __shfl_xor(e, 1);
            s += __shfl_xor(s, 2);
            s += __shfl_xor(s, 4);
            int q = kg * 4 + r;
            sWf[q * 256 + hh * 32 + l * 8 + p] = e / s;
        }
    }
    __syncthreads();

    // ---- Pass loop over hh-pairs {2k, 2k+1} ----
    const int dd2 = t & 15, hhpS = (t >> 4) & 1, qp = t >> 5;

    for (int k = 0; k < 4; ++k) {
        // -- dump: wave k writes its off-logits to offL[q][col] (verified D map) --
        if (wv == k) {
            #pragma unroll
            for (int j = 0; j < 8; ++j)
                #pragma unroll
                for (int r = 0; r < 4; ++r)
                    offL[(kg * 4 + r) * 132 + j * 16 + mrow] = accO[j][r];
        }
        __syncthreads();

        // -- pack: all 256 threads, 4 samples each, plain index math --
        #pragma unroll
        for (int it = 0; it < 4; ++it) {
            int s = it * 256 + t;               // = q*64 + hhL*32 + l*8 + p
            int q = s >> 6, hhL = (s >> 5) & 1, l = (s >> 3) & 3, p = s & 7;
            const int Wl = 128 >> l;
            const float scl = 0.5f * (float)(Wl - 1);
            float lx = offL[q * 132 + hhL * 64 + l * 16 + p * 2];
            float ly = offL[q * 132 + hhL * 64 + l * 16 + p * 2 + 1];
            float w  = sWf[q * 256 + (2 * k + hhL) * 32 + l * 8 + p];
            float rx = sR[q * 8 + l * 2], ry = sR[q * 8 + l * 2 + 1];
            float cx = rx + fast_tanh(lx) * 0.25f;
            float cy = ry + fast_tanh(ly) * 0.25f;
            float xx = (cx + 1.f) * scl, yy = (cy + 1.f) * scl;
            float x0f = floorf(xx), y0f = floorf(yy);
            float fx = xx - x0f, fy = yy - y0f;
            int x0 = (int)x0f, y0 = (int)y0f;
            int xc0 = min(max(x0, 0), Wl - 1);
            int xc1 = min(max(x0 + 1, 0), Wl - 1);
            int yc0 = min(max(y0, 0), Wl - 1);
            int yc1 = min(max(y0 + 1, 0), Wl - 1);
            bool bx0 = (x0 >= 0) & (x0 < Wl);
            bool bx1 = (x0 + 1 >= 0) & (x0 + 1 < Wl);
            bool by0 = (y0 >= 0) & (y0 < Wl);
            bool by1 = (y0 + 1 >= 0) & (y0 + 1 < Wl);
            float w00 = (bx0 && by0) ? (1.f - fx) * (1.f - fy) * w : 0.f;
            float w01 = (bx1 && by0) ? fx * (1.f - fy) * w : 0.f;
            float w10 = (bx0 && by1) ? (1.f - fx) * fy * w : 0.f;
            float w11 = (bx1 && by1) ? fx * fy * w : 0.f;
            unsigned pw = (unsigned)(yc0 * Wl + xc0)
                        | ((unsigned)(xc1 - xc0) << 14)
                        | ((unsigned)(yc1 - yc0) << 15);
            sPI[s] = pw;
            __half2 hA = __floats2half2_rn(w00, w01);
            __half2 hB = __floats2half2_rn(w10, w11);
            sPWh[s] = make_uint2(*(unsigned*)&hA, *(unsigned*)&hB);
        }
        __syncthreads();

        // -- sample: 16 lanes per sample (channel pairs), fp32 blend --
        {
            const int hh = 2 * k + hhpS;
            #pragma unroll
            for (int qi2 = 0; qi2 < 2; ++qi2) {
                int qi = qp * 2 + qi2;
                float accx = 0.f, accy = 0.f;
                #pragma unroll
                for (int l = 0; l < 4; ++l) {
                    const int Wl = HLa[l];
                    const __half2* vl = (const __half2*)(v + VB[l] + hh * HWa[l] * 32 + dd2 * 2);
                    int sbase = ((qi * 2 + hhpS) * 4 + l) * 8;
                    #pragma unroll
                    for (int p = 0; p < 8; ++p) {
                        unsigned pw = sPI[sbase + p];
                        uint2 ww = sPWh[sbase + p];
                        float2 fa = __half22float2(*(__half2*)&ww.x);   // (w00, w01)
                        float2 fb = __half22float2(*(__half2*)&ww.y);   // (w10, w11)
                        int idx = pw & 0x3FFF;
                        int dxo = ((pw >> 14) & 1) * 16;
                        int dyo = ((pw >> 15) & 1) * (Wl * 16);
                        const __half2* b00 = vl + idx * 16;
                        float2 f00 = __half22float2(b00[0]);
                        float2 f01 = __half22float2(b00[dxo]);
                        float2 f10 = __half22float2(b00[dyo]);
                        float2 f11 = __half22float2(b00[dxo + dyo]);
                        accx += fa.x * f00.x + fa.y * f01.x + fb.x * f10.x + fb.y * f11.x;
                        accy += fa.x * f00.y + fa.y * f01.y + fb.x * f10.y + fb.y * f11.y;
                    }
                }
                // preT cols [64k, 64k+64) — attn-weight cols for passes > k
                // live at >= 64(k+1): disjoint.
                *(float2*)(sWf + qi * 256 + hh * 32 + dd2 * 2) = make_float2(accx, accy);
            }
        }
        __syncthreads();
    }

    // ---- E-stage: preT (fp32) -> bf16 hi/lo, then MFMA out projection ----
    {
        int q = t >> 4, c0 = (t & 15) * 16;
        #pragma unroll
        for (int j = 0; j < 16; ++j) {
            float x = sWf[q * 256 + c0 + j];
            short hi = bf16hi(x);
            sQh[q * 264 + c0 + j] = hi;
            sQl[q * 264 + c0 + j] = bf16hi(x - bf16f(hi));
        }
    }
    __syncthreads();

    {
        f32x4 accE[4];
        f32x4 z = {0.f, 0.f, 0.f, 0.f};
        #pragma unroll
        for (int e = 0; e < 4; ++e) accE[e] = z;
        const short* outH = WtH + (768 + wv * 64 + mrow) * 256 + kg * 8;
        const short* outL = WtL + (768 + wv * 64 + mrow) * 256 + kg * 8;
        const int aoff = mrow * 264 + kg * 8;
        #pragma unroll
        for (int kk = 0; kk < 8; ++kk) {
            s16x8 ah = *(const s16x8*)(sQh + aoff + kk * 32);
            s16x8 al = *(const s16x8*)(sQl + aoff + kk * 32);
            #pragma unroll
            for (int e = 0; e < 4; ++e) {
                s16x8 bh = *(const s16x8*)(outH + e * 4096 + kk * 32);
                s16x8 bl = *(const s16x8*)(outL + e * 4096 + kk * 32);
                accE[e] = MFMA16(ah, bh, accE[e]);
                accE[e] = MFMA16(al, bh, accE[e]);
                accE[e] = MFMA16(ah, bl, accE[e]);
            }
        }
        #pragma unroll
        for (int e = 0; e < 4; ++e) {
            int col = wv * 64 + e * 16 + mrow;
            float bb = bout[col];
            #pragma unroll
            for (int r = 0; r < 4; ++r)
                out[(n0 + kg * 4 + r) * 256 + col] = accE[e][r] + bb;
        }
    }
}

// ---------------------------------------------------------------------------
extern "C" void kernel_launch(void* const* d_in, const int* in_sizes, int n_in,
                              void* d_out, int out_size, void* d_ws, size_t ws_size,
                              hipStream_t stream) {
    const float* query = (const float*)d_in[0];
    const float* refp  = (const float*)d_in[1];
    const float* f0    = (const float*)d_in[2];
    const float* f1    = (const float*)d_in[3];
    const float* f2    = (const float*)d_in[4];
    const float* f3    = (const float*)d_in[5];
    const float* Woff  = (const float*)d_in[6];
    const float* boff  = (const float*)d_in[7];
    const float* Wattn = (const float*)d_in[8];
    const float* battn = (const float*)d_in[9];
    const float* Wval  = (const float*)d_in[10];
    const float* bval  = (const float*)d_in[11];
    const float* Wout  = (const float*)d_in[12];
    const float* bout  = (const float*)d_in[13];

    __half* v  = (__half*)d_ws;                              // 11,141,120 B
    short* WtH = (short*)((char*)d_ws + 11141120);           //    524,288 B
    short* WtL = WtH + 262144;                               //    524,288 B
    float* outp = (float*)d_out;

    prep_w<<<1024, 256, 0, stream>>>(Woff, Wattn, Wout, WtH, WtL);
    vproj_kernel<<<1360, 256, 0, stream>>>(f0, f1, f2, f3, Wval, bval, v);
    msda_kernel<<<2500, 256, 0, stream>>>(query, refp, boff, battn, bout,
                                          WtH, WtL, v, outp);
}